// Round 4
// baseline (200.314 us; speedup 1.0000x reference)
//
#include <hip/hip_runtime.h>
#include <hip/hip_bf16.h>
#include <math.h>

// Problem constants
#define B_ 4
#define C_ 256
#define H_ 64
#define W_ 64
#define COMP_ 64
#define K2_ 25
#define HW_ (H_*W_)   // 4096
#define EPS_ 1e-5f

// ---------------------------------------------------------------------------
// Kernel T: weight layout transforms (scalar-load-friendly).
//   wTc[c*64+o]                = w_comp[o*256+c]
//   wTe[((o*9+q)*4+s2)*25+k2]  = w_enc[((k2*4+s2)*64+o)*9+q]
// ---------------------------------------------------------------------------
__global__ void k_transpose(const float* __restrict__ w_comp,
                            const float* __restrict__ w_enc,
                            float* __restrict__ wTc,
                            float* __restrict__ wTe) {
    int t = blockIdx.x * 256 + threadIdx.x;
    if (t < COMP_ * C_) {
        int o = t & 63;
        int c = t >> 6;
        wTc[t] = w_comp[o * C_ + c];
    } else {
        int t2 = t - COMP_ * C_;
        if (t2 < 100 * COMP_ * 9) {
            int k2 = t2 % 25;
            int r = t2 / 25;
            int s2 = r & 3; r >>= 2;
            int q = r % 9;
            int o = r / 9;
            wTe[t2] = w_enc[(((k2 * 4 + s2) * COMP_) + o) * 9 + q];
        }
    }
}

// ---------------------------------------------------------------------------
// Kernel A: 1x1 compression (256->64) + BN + SiLU.
// grid (64 px-tiles, B), block (64 px, 4 og, 4 cg) = 1024 thr = 16 waves.
// Thread: 16 outputs over 64 channels; 4-way LDS tree reduction.
// ---------------------------------------------------------------------------
__global__ void __launch_bounds__(1024)
k_compress(const float* __restrict__ x, const float* __restrict__ wTc,
           const float* __restrict__ gamma, const float* __restrict__ beta,
           const float* __restrict__ mean, const float* __restrict__ var,
           float* __restrict__ act) {
    __shared__ float redA[COMP_ * 64];             // 16 KB
    __shared__ float redB[COMP_ * 64];             // 16 KB
    const int tx = threadIdx.x;                    // px
    const int ty = threadIdx.y;                    // og
    const int tz = threadIdx.z;                    // cg
    const int ogu = __builtin_amdgcn_readfirstlane(ty);
    const int cgu = __builtin_amdgcn_readfirstlane(tz);
    const int b = blockIdx.y;
    const int p0 = blockIdx.x * 64;

    float acc[16];
#pragma unroll
    for (int k = 0; k < 16; ++k) acc[k] = 0.f;

    const float* xb = x + (size_t)b * C_ * HW_ + p0 + tx;
#pragma unroll 4
    for (int cl = 0; cl < 64; ++cl) {
        int c = cgu * 64 + cl;                     // uniform
        float xv = xb[c * HW_];
        const float* w = wTc + c * COMP_ + ogu * 16;  // uniform -> s_load
#pragma unroll
        for (int k = 0; k < 16; ++k)
            acc[k] = fmaf(w[k], xv, acc[k]);
    }

    // 4-way tree reduction: cg1->A, cg2->B; cg0+=A, cg3+=B; cg3->A; cg0+=A
    if (tz == 1) {
#pragma unroll
        for (int k = 0; k < 16; ++k) redA[(ty * 16 + k) * 64 + tx] = acc[k];
    } else if (tz == 2) {
#pragma unroll
        for (int k = 0; k < 16; ++k) redB[(ty * 16 + k) * 64 + tx] = acc[k];
    }
    __syncthreads();
    if (tz == 0) {
#pragma unroll
        for (int k = 0; k < 16; ++k) acc[k] += redA[(ty * 16 + k) * 64 + tx];
    } else if (tz == 3) {
#pragma unroll
        for (int k = 0; k < 16; ++k) acc[k] += redB[(ty * 16 + k) * 64 + tx];
    }
    __syncthreads();
    if (tz == 3) {
#pragma unroll
        for (int k = 0; k < 16; ++k) redA[(ty * 16 + k) * 64 + tx] = acc[k];
    }
    __syncthreads();
    if (tz == 0) {
#pragma unroll
        for (int k = 0; k < 16; ++k) {
            int o = ty * 16 + k;
            float s = acc[k] + redA[o * 64 + tx];
            float iv = gamma[o] * rsqrtf(var[o] + EPS_);
            float bn = (s - mean[o]) * iv + beta[o];
            float sg = 1.f / (1.f + __expf(-bn));
            act[((b * COMP_ + o) * HW_) + p0 + tx] = bn * sg;
        }
    }
}

// ---------------------------------------------------------------------------
// Kernel B: 3x3 encoder conv (64->100) + softmax(25).
// grid (64 i, B), block (64 j, 4 s2, 4 og) = 1024 thr = 16 waves.
// Thread: 25 logits over its 16-channel quarter; 4-way LDS reduction;
// softmax + coalesced strided store in og0. Output layout [b][k2*4+s2][i][j].
// ---------------------------------------------------------------------------
__global__ void __launch_bounds__(1024)
k_encoder(const float* __restrict__ act, const float* __restrict__ wTe,
          float* __restrict__ mask) {
    __shared__ float sact[12800];                  // 51.2 KB (staging 12672, then 2x6400 bufs)
    const int tx = threadIdx.x;                    // j
    const int ty = threadIdx.y;                    // s2
    const int tz = threadIdx.z;                    // og
    const int tid = (tz * 4 + ty) * 64 + tx;
    const int i = blockIdx.x;
    const int b = blockIdx.y;
    const int s2u = __builtin_amdgcn_readfirstlane(ty);
    const int ogu = __builtin_amdgcn_readfirstlane(tz);

    // stage act rows i-1..i+1 with zero halo: [row][o][col(=gj+1)], 3*64*66
    const float* ab = act + (size_t)b * COMP_ * HW_;
    for (int t = tid; t < 3 * COMP_ * 66; t += 1024) {
        int col = t % 66;
        int r = t / 66;
        int o = r & 63;
        int row = r >> 6;
        int gi = i + row - 1;
        int gj = col - 1;
        float v = 0.f;
        if ((unsigned)gi < 64u && (unsigned)gj < 64u)
            v = ab[(o * H_ + gi) * W_ + gj];
        sact[t] = v;
    }
    __syncthreads();

    float acc[K2_];
#pragma unroll
    for (int k = 0; k < K2_; ++k) acc[k] = 0.f;

#pragma unroll 1
    for (int oi = 0; oi < 16; ++oi) {
        int o = ogu * 16 + oi;                     // uniform
#pragma unroll
        for (int q = 0; q < 9; ++q) {
            const int dy = q / 3, dx = q % 3;
            float a = sact[(dy * COMP_ + o) * 66 + tx + dx];
            const float* w = wTe + ((o * 9 + q) * 4 + s2u) * 25;  // uniform
#pragma unroll
            for (int k = 0; k < K2_; ++k)
                acc[k] = fmaf(w[k], a, acc[k]);
        }
    }
    __syncthreads();                               // sact reads done

    float* bufA = sact;                            // 6400 dw
    float* bufB = sact + 6400;                     // 6400 dw
    const int rix = ty * 64 + tx;                  // 0..255
    if (tz == 1) {
#pragma unroll
        for (int k = 0; k < K2_; ++k) bufA[k * 256 + rix] = acc[k];
    } else if (tz == 2) {
#pragma unroll
        for (int k = 0; k < K2_; ++k) bufB[k * 256 + rix] = acc[k];
    }
    __syncthreads();
    if (tz == 0) {
#pragma unroll
        for (int k = 0; k < K2_; ++k) acc[k] += bufA[k * 256 + rix];
    } else if (tz == 3) {
#pragma unroll
        for (int k = 0; k < K2_; ++k) acc[k] += bufB[k * 256 + rix];
    }
    __syncthreads();
    if (tz == 3) {
#pragma unroll
        for (int k = 0; k < K2_; ++k) bufA[k * 256 + rix] = acc[k];
    }
    __syncthreads();
    if (tz == 0) {
#pragma unroll
        for (int k = 0; k < K2_; ++k) acc[k] += bufA[k * 256 + rix];

        // softmax over 25
        float mx = acc[0];
#pragma unroll
        for (int k = 1; k < K2_; ++k) mx = fmaxf(mx, acc[k]);
        float sum = 0.f;
#pragma unroll
        for (int k = 0; k < K2_; ++k) { acc[k] = __expf(acc[k] - mx); sum += acc[k]; }
        float rs = 1.f / sum;

        // coalesced strided stores: mask[b][(k2*4+s2)][i][j]
        float* mb = mask + (size_t)b * 100 * HW_ + i * W_ + tx;
#pragma unroll
        for (int k = 0; k < K2_; ++k)
            mb[(k * 4 + ty) * HW_] = acc[k] * rs;
    }
}

// ---------------------------------------------------------------------------
// Kernel C: reassembly + pixel shuffle.
// grid (64 i, 16 cc, B), block (64 j, 4 cq). Thread: 4 ch x 4 subpx.
// x tile in LDS: [r][col][ch pad 20] with quad-XOR swizzle (ch ^ 8*((col>>3)&1))
//   -> b128 reads & b32 staging writes are 2-way max (free).
// mask read straight from global (coalesced b32, L2-resident, no lane reuse).
// ---------------------------------------------------------------------------
__global__ void __launch_bounds__(256)
k_reassemble(const float* __restrict__ x, const float* __restrict__ mask,
             float* __restrict__ out) {
    __shared__ __align__(16) float sx[5 * 68 * 20];   // 27.2 KB
    const int tx = threadIdx.x;                    // j
    const int ty = threadIdx.y;                    // ch-quad
    const int tid = ty * 64 + tx;
    const int i = blockIdx.x;
    const int cc = blockIdx.y;
    const int b = blockIdx.z;

    // x tile [r][col][ch^swz], zero halo
    const float* xb = x + ((size_t)b * C_ + cc * 16) * HW_;
    for (int e = tid; e < 16 * 340; e += 256) {
        int ch = e / 340;
        int rc = e - ch * 340;
        int r = rc / 68;
        int col = rc - r * 68;
        int gi = i + r - 2;
        int gj = col - 2;
        float v = 0.f;
        if ((unsigned)gi < 64u && (unsigned)gj < 64u)
            v = xb[ch * HW_ + gi * W_ + gj];
        sx[rc * 20 + (ch ^ (((col >> 3) & 1) << 3))] = v;
    }
    __syncthreads();

    float acc[4][4];
#pragma unroll
    for (int cl = 0; cl < 4; ++cl)
#pragma unroll
        for (int s = 0; s < 4; ++s) acc[cl][s] = 0.f;

    const float* mrow = mask + (size_t)b * 100 * HW_ + i * W_ + tx;

#pragma unroll
    for (int dy = 0; dy < 5; ++dy) {
#pragma unroll
        for (int dx = 0; dx < 5; ++dx) {
            const int k2 = dy * 5 + dx;
            const int u = tx + dx;
            float4 xq = *(const float4*)&sx[(dy * 68 + u) * 20 +
                                            ((ty * 4) ^ (((u >> 3) & 1) << 3))];
            float m0 = mrow[(k2 * 4 + 0) * HW_];
            float m1 = mrow[(k2 * 4 + 1) * HW_];
            float m2 = mrow[(k2 * 4 + 2) * HW_];
            float m3 = mrow[(k2 * 4 + 3) * HW_];
            acc[0][0] = fmaf(xq.x, m0, acc[0][0]);
            acc[0][1] = fmaf(xq.x, m1, acc[0][1]);
            acc[0][2] = fmaf(xq.x, m2, acc[0][2]);
            acc[0][3] = fmaf(xq.x, m3, acc[0][3]);
            acc[1][0] = fmaf(xq.y, m0, acc[1][0]);
            acc[1][1] = fmaf(xq.y, m1, acc[1][1]);
            acc[1][2] = fmaf(xq.y, m2, acc[1][2]);
            acc[1][3] = fmaf(xq.y, m3, acc[1][3]);
            acc[2][0] = fmaf(xq.z, m0, acc[2][0]);
            acc[2][1] = fmaf(xq.z, m1, acc[2][1]);
            acc[2][2] = fmaf(xq.z, m2, acc[2][2]);
            acc[2][3] = fmaf(xq.z, m3, acc[2][3]);
            acc[3][0] = fmaf(xq.w, m0, acc[3][0]);
            acc[3][1] = fmaf(xq.w, m1, acc[3][1]);
            acc[3][2] = fmaf(xq.w, m2, acc[3][2]);
            acc[3][3] = fmaf(xq.w, m3, acc[3][3]);
        }
    }

#pragma unroll
    for (int cl = 0; cl < 4; ++cl) {
        int c = cc * 16 + ty * 4 + cl;
        float* op = out + (((size_t)(b * C_ + c) * 128 + 2 * i) * 128) + 2 * tx;
        *(float2*)op         = float2{acc[cl][0], acc[cl][1]};
        *(float2*)(op + 128) = float2{acc[cl][2], acc[cl][3]};
    }
}

// ---------------------------------------------------------------------------
extern "C" void kernel_launch(void* const* d_in, const int* in_sizes, int n_in,
                              void* d_out, int out_size, void* d_ws, size_t ws_size,
                              hipStream_t stream) {
    const float* x       = (const float*)d_in[0];
    const float* w_comp  = (const float*)d_in[1];
    const float* bn_g    = (const float*)d_in[2];
    const float* bn_b    = (const float*)d_in[3];
    const float* bn_m    = (const float*)d_in[4];
    const float* bn_v    = (const float*)d_in[5];
    const float* w_enc   = (const float*)d_in[6];
    float* out = (float*)d_out;

    float* ws   = (float*)d_ws;
    float* wTc  = ws;                              // 16384 floats
    float* wTe  = ws + 16384;                      // 57600 floats
    float* act  = ws + 16384 + 57600;              // 1,048,576 floats
    float* mask = act + (size_t)B_ * COMP_ * HW_;  // 1,638,400 floats

    k_transpose<<<289, 256, 0, stream>>>(w_comp, w_enc, wTc, wTe);
    k_compress<<<dim3(64, B_), dim3(64, 4, 4), 0, stream>>>(x, wTc, bn_g, bn_b, bn_m, bn_v, act);
    k_encoder<<<dim3(64, B_), dim3(64, 4, 4), 0, stream>>>(act, wTe, mask);
    k_reassemble<<<dim3(64, 16, B_), dim3(64, 4), 0, stream>>>(x, mask, out);
}

// Round 5
// 171.674 us; speedup vs baseline: 1.1668x; 1.1668x over previous
//
#include <hip/hip_runtime.h>
#include <hip/hip_bf16.h>
#include <math.h>

// Problem constants
#define B_ 4
#define C_ 256
#define H_ 64
#define W_ 64
#define COMP_ 64
#define K2_ 25
#define HW_ (H_*W_)   // 4096
#define EPS_ 1e-5f
#define WTE_STRIDE 26  // 25 k2 values padded to 26 for 8B-aligned float2 loads

typedef float v2f __attribute__((ext_vector_type(2)));
#define FMA2(a, b, c) __builtin_elementwise_fma((a), (b), (c))

// ---------------------------------------------------------------------------
// Kernel T: weight layout transforms (scalar-load-friendly).
//   wTc[c*64+o]                        = w_comp[o*256+c]
//   wTe[((o*9+q)*4+s2)*26 + k2]        = w_enc[((k2*4+s2)*64+o)*9+q]
// ---------------------------------------------------------------------------
__global__ void k_transpose(const float* __restrict__ w_comp,
                            const float* __restrict__ w_enc,
                            float* __restrict__ wTc,
                            float* __restrict__ wTe) {
    int t = blockIdx.x * 256 + threadIdx.x;
    if (t < COMP_ * C_) {
        int o = t & 63;
        int c = t >> 6;
        wTc[t] = w_comp[o * C_ + c];
    } else {
        int t2 = t - COMP_ * C_;
        if (t2 < 100 * COMP_ * 9) {
            int k2 = t2 % 25;
            int r = t2 / 25;
            int s2 = r & 3; r >>= 2;
            int q = r % 9;
            int o = r / 9;
            wTe[((o * 9 + q) * 4 + s2) * WTE_STRIDE + k2] =
                w_enc[(((k2 * 4 + s2) * COMP_) + o) * 9 + q];
        }
    }
}

// ---------------------------------------------------------------------------
// Kernel A: 1x1 compression (256->64) + BN + SiLU.  Packed v2f math.
// grid (64 px-tiles, B), block (64 px, 4 og, 4 cg) = 1024 thr = 16 waves.
// ---------------------------------------------------------------------------
__global__ void __launch_bounds__(1024)
k_compress(const float* __restrict__ x, const float* __restrict__ wTc,
           const float* __restrict__ gamma, const float* __restrict__ beta,
           const float* __restrict__ mean, const float* __restrict__ var,
           float* __restrict__ act) {
    __shared__ v2f redA[32 * 64];                  // 16 KB
    __shared__ v2f redB[32 * 64];                  // 16 KB
    const int tx = threadIdx.x;                    // px
    const int ty = threadIdx.y;                    // og
    const int tz = threadIdx.z;                    // cg
    const int ogu = __builtin_amdgcn_readfirstlane(ty);
    const int cgu = __builtin_amdgcn_readfirstlane(tz);
    const int b = blockIdx.y;
    const int p0 = blockIdx.x * 64;

    v2f acc2[8];
#pragma unroll
    for (int k = 0; k < 8; ++k) acc2[k] = (v2f){0.f, 0.f};

    const float* xb = x + (size_t)b * C_ * HW_ + p0 + tx;
#pragma unroll 4
    for (int cl = 0; cl < 64; ++cl) {
        int c = cgu * 64 + cl;                     // uniform
        float xv = xb[c * HW_];
        const v2f* w2 = (const v2f*)(wTc + c * COMP_ + ogu * 16);  // uniform
        v2f xv2 = (v2f){xv, xv};
#pragma unroll
        for (int k = 0; k < 8; ++k)
            acc2[k] = FMA2(xv2, w2[k], acc2[k]);
    }

    const int rbase = ty * 8;
    // 4-way tree: cg1->A, cg2->B; cg0+=A, cg3+=B; cg3->A; cg0+=A
    if (tz == 1) {
#pragma unroll
        for (int k = 0; k < 8; ++k) redA[(rbase + k) * 64 + tx] = acc2[k];
    } else if (tz == 2) {
#pragma unroll
        for (int k = 0; k < 8; ++k) redB[(rbase + k) * 64 + tx] = acc2[k];
    }
    __syncthreads();
    if (tz == 0) {
#pragma unroll
        for (int k = 0; k < 8; ++k) acc2[k] += redA[(rbase + k) * 64 + tx];
    } else if (tz == 3) {
#pragma unroll
        for (int k = 0; k < 8; ++k) acc2[k] += redB[(rbase + k) * 64 + tx];
    }
    __syncthreads();
    if (tz == 3) {
#pragma unroll
        for (int k = 0; k < 8; ++k) redA[(rbase + k) * 64 + tx] = acc2[k];
    }
    __syncthreads();
    if (tz == 0) {
#pragma unroll
        for (int k = 0; k < 8; ++k) {
            v2f s = acc2[k] + redA[(rbase + k) * 64 + tx];
            int o0 = ty * 16 + 2 * k;
#pragma unroll
            for (int h = 0; h < 2; ++h) {
                int o = o0 + h;
                float sv = (h == 0) ? s.x : s.y;
                float iv = gamma[o] * rsqrtf(var[o] + EPS_);
                float bn = (sv - mean[o]) * iv + beta[o];
                float sg = 1.f / (1.f + __expf(-bn));
                act[((b * COMP_ + o) * HW_) + p0 + tx] = bn * sg;
            }
        }
    }
}

// ---------------------------------------------------------------------------
// Kernel B: 3x3 encoder conv (64->100) + softmax(25) + transpose-out.
// grid (64 i, B), block (64 j, 4 s2, 4 og) = 1024 thr.  Packed v2f math:
// 12 pk-fma + 1 fma per (o,q).  Output maskT[b][(i*64+j)*100 + k2*4+s2]
// via in-LDS transpose + coalesced float4 copy.
// ---------------------------------------------------------------------------
__global__ void __launch_bounds__(1024)
k_encoder(const float* __restrict__ act, const float* __restrict__ wTe,
          float* __restrict__ maskT) {
    __shared__ float sact[13312];                  // 53.2 KB
    const int tx = threadIdx.x;                    // j
    const int ty = threadIdx.y;                    // s2
    const int tz = threadIdx.z;                    // og
    const int tid = (tz * 4 + ty) * 64 + tx;
    const int i = blockIdx.x;
    const int b = blockIdx.y;
    const int s2u = __builtin_amdgcn_readfirstlane(ty);
    const int ogu = __builtin_amdgcn_readfirstlane(tz);

    // stage act rows i-1..i+1 with zero halo: [row][o][col(=gj+1)], 3*64*66
    const float* ab = act + (size_t)b * COMP_ * HW_;
    for (int t = tid; t < 3 * COMP_ * 66; t += 1024) {
        int col = t % 66;
        int r = t / 66;
        int o = r & 63;
        int row = r >> 6;
        int gi = i + row - 1;
        int gj = col - 1;
        float v = 0.f;
        if ((unsigned)gi < 64u && (unsigned)gj < 64u)
            v = ab[(o * H_ + gi) * W_ + gj];
        sact[t] = v;
    }
    __syncthreads();

    v2f acc2[13];
#pragma unroll
    for (int k = 0; k < 13; ++k) acc2[k] = (v2f){0.f, 0.f};

#pragma unroll 1
    for (int oi = 0; oi < 16; ++oi) {
        int o = ogu * 16 + oi;                     // uniform
#pragma unroll
        for (int q = 0; q < 9; ++q) {
            const int dy = q / 3, dx = q % 3;
            float a = sact[(dy * COMP_ + o) * 66 + tx + dx];
            const float* wb = wTe + ((o * 9 + q) * 4 + s2u) * WTE_STRIDE;  // uniform
            const v2f* w2 = (const v2f*)wb;
            v2f a2 = (v2f){a, a};
#pragma unroll
            for (int k = 0; k < 12; ++k)
                acc2[k] = FMA2(a2, w2[k], acc2[k]);
            acc2[12].x = fmaf(wb[24], a, acc2[12].x);
        }
    }
    __syncthreads();                               // sact reads done

    v2f* bufA = (v2f*)sact;                        // 3328 v2f
    v2f* bufB = bufA + 3328;                       // 3328 v2f
    const int rix = ty * 64 + tx;                  // 0..255
    if (tz == 1) {
#pragma unroll
        for (int k = 0; k < 13; ++k) bufA[k * 256 + rix] = acc2[k];
    } else if (tz == 2) {
#pragma unroll
        for (int k = 0; k < 13; ++k) bufB[k * 256 + rix] = acc2[k];
    }
    __syncthreads();
    if (tz == 0) {
#pragma unroll
        for (int k = 0; k < 13; ++k) acc2[k] += bufA[k * 256 + rix];
    } else if (tz == 3) {
#pragma unroll
        for (int k = 0; k < 13; ++k) acc2[k] += bufB[k * 256 + rix];
    }
    __syncthreads();
    if (tz == 3) {
#pragma unroll
        for (int k = 0; k < 13; ++k) bufA[k * 256 + rix] = acc2[k];
    }
    __syncthreads();
    float ex[K2_];
    if (tz == 0) {
#pragma unroll
        for (int k = 0; k < 13; ++k) acc2[k] += bufA[k * 256 + rix];

        // softmax over 25 (acc2[12].y is junk — ignored)
        float mx = acc2[12].x;
#pragma unroll
        for (int k = 0; k < 12; ++k) mx = fmaxf(mx, fmaxf(acc2[k].x, acc2[k].y));
        float sum = 0.f;
#pragma unroll
        for (int k = 0; k < 12; ++k) {
            ex[2 * k]     = __expf(acc2[k].x - mx);
            ex[2 * k + 1] = __expf(acc2[k].y - mx);
            sum += ex[2 * k] + ex[2 * k + 1];
        }
        ex[24] = __expf(acc2[12].x - mx);
        sum += ex[24];
        float rs = 1.f / sum;
#pragma unroll
        for (int k = 0; k < K2_; ++k) ex[k] *= rs;
    }
    __syncthreads();                               // bufA reads done before reuse

    float* st = sact;                              // transpose buffer [j][100]
    if (tz == 0) {
#pragma unroll
        for (int k = 0; k < K2_; ++k)
            st[tx * 100 + k * 4 + ty] = ex[k];     // 2-way banks: free
    }
    __syncthreads();

    // coalesced write: maskT[b][(i*64+j)*100 + ch]
    float4* dst = (float4*)(maskT + ((size_t)b * HW_ + i * 64) * 100);
    const float4* src = (const float4*)st;
    for (int t = tid; t < 1600; t += 1024)
        dst[t] = src[t];
}

// ---------------------------------------------------------------------------
// Kernel C: reassembly + pixel shuffle.
// grid (64 i, 16 cc, B), block (64 j, 4 cq). Thread: 4 ch x 4 subpx.
// sx [r][col][ch pad20]: staged via ds_write_b128 (conflict-free, same 8-lane
// bank tiling as the reads).  smask [j][100] bulk float4 copy, b128 reads
// conflict-free.  k2+1 prefetch; packed v2f fmas.
// ---------------------------------------------------------------------------
__global__ void __launch_bounds__(256)
k_reassemble(const float* __restrict__ x, const float* __restrict__ maskT,
             float* __restrict__ out) {
    __shared__ __align__(16) float smask[64 * 100];   // 25.6 KB
    __shared__ __align__(16) float sx[5 * 68 * 20];   // 27.2 KB
    const int tx = threadIdx.x;                    // j
    const int ty = threadIdx.y;                    // ch-quad
    const int tid = ty * 64 + tx;
    const int i = blockIdx.x;
    const int cc = blockIdx.y;
    const int b = blockIdx.z;

    // ---- mask row: fully coalesced float4 copy (1600 float4) ----
    {
        const float4* src = (const float4*)(maskT + ((size_t)b * HW_ + i * 64) * 100);
        float4* dst = (float4*)smask;
#pragma unroll
        for (int t = 0; t < 7; ++t) {
            int e = tid + t * 256;
            if (e < 1600) dst[e] = src[e];
        }
    }

    // ---- x tile: per-thread float4 of 4 channels -> ds_write_b128 ----
    const float* xb = x + ((size_t)b * C_ + cc * 16 + ty * 4) * HW_;
#pragma unroll
    for (int r = 0; r < 5; ++r) {
        const int gi = i + r - 2;                  // uniform
        const bool rowok = ((unsigned)gi < 64u);   // uniform branch
        {
            float4 v = {0.f, 0.f, 0.f, 0.f};
            int gj = tx - 2;
            if (rowok && gj >= 0) {                // gj <= 61 always
                const float* p = xb + gi * W_ + gj;
                v.x = p[0];
                v.y = p[HW_];
                v.z = p[2 * HW_];
                v.w = p[3 * HW_];
            }
            *(float4*)&sx[(r * 68 + tx) * 20 + ty * 4] = v;
        }
        if (tid < 16) {                            // tail cols 64..67
            int q = tid >> 2;
            int col = 64 + (tid & 3);
            int gj = col - 2;                      // 62..65
            float4 v = {0.f, 0.f, 0.f, 0.f};
            if (rowok && gj < 64) {
                const float* p = x + ((size_t)b * C_ + cc * 16 + q * 4) * HW_ + gi * W_ + gj;
                v.x = p[0];
                v.y = p[HW_];
                v.z = p[2 * HW_];
                v.w = p[3 * HW_];
            }
            *(float4*)&sx[(r * 68 + col) * 20 + q * 4] = v;
        }
    }
    __syncthreads();

    v2f a01[4], a23[4];
#pragma unroll
    for (int cl = 0; cl < 4; ++cl) { a01[cl] = (v2f){0.f, 0.f}; a23[cl] = (v2f){0.f, 0.f}; }

    // prefetch k2=0
    float4 xq = *(const float4*)&sx[(0 * 68 + tx + 0) * 20 + ty * 4];
    float4 m  = *(const float4*)&smask[tx * 100 + 0];

#pragma unroll
    for (int k2 = 0; k2 < K2_; ++k2) {
        float4 xq_c = xq, m_c = m;
        if (k2 < K2_ - 1) {
            const int kn = k2 + 1;
            const int dy = kn / 5, dx = kn % 5;
            xq = *(const float4*)&sx[(dy * 68 + tx + dx) * 20 + ty * 4];
            m  = *(const float4*)&smask[tx * 100 + kn * 4];
        }
        v2f m01 = (v2f){m_c.x, m_c.y};
        v2f m23 = (v2f){m_c.z, m_c.w};
        float xc[4] = {xq_c.x, xq_c.y, xq_c.z, xq_c.w};
#pragma unroll
        for (int cl = 0; cl < 4; ++cl) {
            v2f xv2 = (v2f){xc[cl], xc[cl]};
            a01[cl] = FMA2(xv2, m01, a01[cl]);
            a23[cl] = FMA2(xv2, m23, a23[cl]);
        }
    }

#pragma unroll
    for (int cl = 0; cl < 4; ++cl) {
        int c = cc * 16 + ty * 4 + cl;
        float* op = out + (((size_t)(b * C_ + c) * 128 + 2 * i) * 128) + 2 * tx;
        *(float2*)op         = float2{a01[cl].x, a01[cl].y};
        *(float2*)(op + 128) = float2{a23[cl].x, a23[cl].y};
    }
}

// ---------------------------------------------------------------------------
extern "C" void kernel_launch(void* const* d_in, const int* in_sizes, int n_in,
                              void* d_out, int out_size, void* d_ws, size_t ws_size,
                              hipStream_t stream) {
    const float* x       = (const float*)d_in[0];
    const float* w_comp  = (const float*)d_in[1];
    const float* bn_g    = (const float*)d_in[2];
    const float* bn_b    = (const float*)d_in[3];
    const float* bn_m    = (const float*)d_in[4];
    const float* bn_v    = (const float*)d_in[5];
    const float* w_enc   = (const float*)d_in[6];
    float* out = (float*)d_out;

    float* ws    = (float*)d_ws;
    float* wTc   = ws;                               // 16384 floats
    float* wTe   = ws + 16384;                       // 59904 floats (stride 26)
    float* act   = ws + 16384 + 59904;               // 1,048,576 floats
    float* maskT = act + (size_t)B_ * COMP_ * HW_;   // 1,638,400 floats

    k_transpose<<<289, 256, 0, stream>>>(w_comp, w_enc, wTc, wTe);
    k_compress<<<dim3(64, B_), dim3(64, 4, 4), 0, stream>>>(x, wTc, bn_g, bn_b, bn_m, bn_v, act);
    k_encoder<<<dim3(64, B_), dim3(64, 4, 4), 0, stream>>>(act, wTe, maskT);
    k_reassemble<<<dim3(64, 16, B_), dim3(64, 4), 0, stream>>>(x, maskT, out);
}

// Round 6
// 168.946 us; speedup vs baseline: 1.1857x; 1.0162x over previous
//
#include <hip/hip_runtime.h>
#include <hip/hip_bf16.h>
#include <hip/hip_fp16.h>
#include <math.h>

// Problem constants
#define B_ 4
#define C_ 256
#define H_ 64
#define W_ 64
#define COMP_ 64
#define K2_ 25
#define HW_ (H_*W_)   // 4096
#define EPS_ 1e-5f
#define WTE_STRIDE 26  // 25 k2 values padded to 26 for 8B-aligned float2 loads

typedef float v2f __attribute__((ext_vector_type(2)));
#define FMA2(a, b, c) __builtin_elementwise_fma((a), (b), (c))

// ---------------------------------------------------------------------------
// Kernel T: weight layout transforms (scalar-load-friendly).
//   wTc[c*64+o]                        = w_comp[o*256+c]
//   wTe[((o*9+q)*4+s2)*26 + k2]        = w_enc[((k2*4+s2)*64+o)*9+q]
// ---------------------------------------------------------------------------
__global__ void k_transpose(const float* __restrict__ w_comp,
                            const float* __restrict__ w_enc,
                            float* __restrict__ wTc,
                            float* __restrict__ wTe) {
    int t = blockIdx.x * 256 + threadIdx.x;
    if (t < COMP_ * C_) {
        int o = t & 63;
        int c = t >> 6;
        wTc[t] = w_comp[o * C_ + c];
    } else {
        int t2 = t - COMP_ * C_;
        if (t2 < 100 * COMP_ * 9) {
            int k2 = t2 % 25;
            int r = t2 / 25;
            int s2 = r & 3; r >>= 2;
            int q = r % 9;
            int o = r / 9;
            wTe[((o * 9 + q) * 4 + s2) * WTE_STRIDE + k2] =
                w_enc[(((k2 * 4 + s2) * COMP_) + o) * 9 + q];
        }
    }
}

// ---------------------------------------------------------------------------
// Kernel A: 1x1 compression (256->64) + BN + SiLU.
// grid (64 px-tiles, B), block (64 px, 8 og, 2 cg) = 1024 thr = 16 waves.
// Thread: 8 outputs over 128 channels; single-barrier 2-way LDS reduction.
// ---------------------------------------------------------------------------
__global__ void __launch_bounds__(1024)
k_compress(const float* __restrict__ x, const float* __restrict__ wTc,
           const float* __restrict__ gamma, const float* __restrict__ beta,
           const float* __restrict__ mean, const float* __restrict__ var,
           float* __restrict__ act) {
    __shared__ v2f red[32 * 64];                   // 16 KB
    const int tx = threadIdx.x;                    // px
    const int ty = threadIdx.y;                    // og (0..7)
    const int tz = threadIdx.z;                    // cg (0..1)
    const int ogu = __builtin_amdgcn_readfirstlane(ty);
    const int cgu = __builtin_amdgcn_readfirstlane(tz);
    const int b = blockIdx.y;
    const int p0 = blockIdx.x * 64;

    v2f acc2[4];
#pragma unroll
    for (int k = 0; k < 4; ++k) acc2[k] = (v2f){0.f, 0.f};

    const float* xb = x + (size_t)b * C_ * HW_ + p0 + tx;
#pragma unroll 8
    for (int cl = 0; cl < 128; ++cl) {
        int c = cgu * 128 + cl;                    // uniform
        float xv = xb[c * HW_];
        const v2f* w2 = (const v2f*)(wTc + c * COMP_ + ogu * 8);  // uniform
        v2f xv2 = (v2f){xv, xv};
#pragma unroll
        for (int k = 0; k < 4; ++k)
            acc2[k] = FMA2(xv2, w2[k], acc2[k]);
    }

    if (tz == 1) {
#pragma unroll
        for (int k = 0; k < 4; ++k) red[(ty * 4 + k) * 64 + tx] = acc2[k];
    }
    __syncthreads();
    if (tz == 0) {
#pragma unroll
        for (int k = 0; k < 4; ++k) {
            v2f s = acc2[k] + red[(ty * 4 + k) * 64 + tx];
            int o0 = ty * 8 + 2 * k;
#pragma unroll
            for (int h = 0; h < 2; ++h) {
                int o = o0 + h;
                float sv = (h == 0) ? s.x : s.y;
                float iv = gamma[o] * rsqrtf(var[o] + EPS_);
                float bn = (sv - mean[o]) * iv + beta[o];
                float sg = 1.f / (1.f + __expf(-bn));
                act[((b * COMP_ + o) * HW_) + p0 + tx] = bn * sg;
            }
        }
    }
}

// ---------------------------------------------------------------------------
// Kernel B: 3x3 encoder conv (64->100) + softmax(25) + fp16 transpose-out.
// grid (64 i, B), block (64 j, 4 s2, 4 og) = 1024 thr.  Packed v2f math.
// Output maskT[b][(i*64+j)*100 + k2*4+s2] in fp16 via in-LDS transpose.
// ---------------------------------------------------------------------------
__global__ void __launch_bounds__(1024)
k_encoder(const float* __restrict__ act, const float* __restrict__ wTe,
          __half* __restrict__ maskT) {
    __shared__ float sact[13312];                  // 53.2 KB
    const int tx = threadIdx.x;                    // j
    const int ty = threadIdx.y;                    // s2
    const int tz = threadIdx.z;                    // og
    const int tid = (tz * 4 + ty) * 64 + tx;
    const int i = blockIdx.x;
    const int b = blockIdx.y;
    const int s2u = __builtin_amdgcn_readfirstlane(ty);
    const int ogu = __builtin_amdgcn_readfirstlane(tz);

    // stage act rows i-1..i+1 with zero halo: [row][o][col(=gj+1)], 3*64*66
    const float* ab = act + (size_t)b * COMP_ * HW_;
    for (int t = tid; t < 3 * COMP_ * 66; t += 1024) {
        int col = t % 66;
        int r = t / 66;
        int o = r & 63;
        int row = r >> 6;
        int gi = i + row - 1;
        int gj = col - 1;
        float v = 0.f;
        if ((unsigned)gi < 64u && (unsigned)gj < 64u)
            v = ab[(o * H_ + gi) * W_ + gj];
        sact[t] = v;
    }
    __syncthreads();

    v2f acc2[13];
#pragma unroll
    for (int k = 0; k < 13; ++k) acc2[k] = (v2f){0.f, 0.f};

#pragma unroll 2
    for (int oi = 0; oi < 16; ++oi) {
        int o = ogu * 16 + oi;                     // uniform
#pragma unroll
        for (int q = 0; q < 9; ++q) {
            const int dy = q / 3, dx = q % 3;
            float a = sact[(dy * COMP_ + o) * 66 + tx + dx];
            const float* wb = wTe + ((o * 9 + q) * 4 + s2u) * WTE_STRIDE;  // uniform
            const v2f* w2 = (const v2f*)wb;
            v2f a2 = (v2f){a, a};
#pragma unroll
            for (int k = 0; k < 12; ++k)
                acc2[k] = FMA2(a2, w2[k], acc2[k]);
            acc2[12].x = fmaf(wb[24], a, acc2[12].x);
        }
    }
    __syncthreads();                               // sact reads done

    v2f* bufA = (v2f*)sact;                        // 3328 v2f
    v2f* bufB = bufA + 3328;                       // 3328 v2f
    const int rix = ty * 64 + tx;                  // 0..255
    if (tz == 1) {
#pragma unroll
        for (int k = 0; k < 13; ++k) bufA[k * 256 + rix] = acc2[k];
    } else if (tz == 2) {
#pragma unroll
        for (int k = 0; k < 13; ++k) bufB[k * 256 + rix] = acc2[k];
    }
    __syncthreads();
    if (tz == 0) {
#pragma unroll
        for (int k = 0; k < 13; ++k) acc2[k] += bufA[k * 256 + rix];
    } else if (tz == 3) {
#pragma unroll
        for (int k = 0; k < 13; ++k) acc2[k] += bufB[k * 256 + rix];
    }
    __syncthreads();
    if (tz == 3) {
#pragma unroll
        for (int k = 0; k < 13; ++k) bufA[k * 256 + rix] = acc2[k];
    }
    __syncthreads();
    float ex[K2_];
    if (tz == 0) {
#pragma unroll
        for (int k = 0; k < 13; ++k) acc2[k] += bufA[k * 256 + rix];

        // softmax over 25 (acc2[12].y is junk — ignored)
        float mx = acc2[12].x;
#pragma unroll
        for (int k = 0; k < 12; ++k) mx = fmaxf(mx, fmaxf(acc2[k].x, acc2[k].y));
        float sum = 0.f;
#pragma unroll
        for (int k = 0; k < 12; ++k) {
            ex[2 * k]     = __expf(acc2[k].x - mx);
            ex[2 * k + 1] = __expf(acc2[k].y - mx);
            sum += ex[2 * k] + ex[2 * k + 1];
        }
        ex[24] = __expf(acc2[12].x - mx);
        sum += ex[24];
        float rs = 1.f / sum;
#pragma unroll
        for (int k = 0; k < K2_; ++k) ex[k] *= rs;
    }
    __syncthreads();                               // bufA reads done before reuse

    __half* st = (__half*)sact;                    // transpose buffer [j][100] fp16
    if (tz == 0) {
#pragma unroll
        for (int k = 0; k < K2_; ++k)
            st[tx * 100 + k * 4 + ty] = __float2half(ex[k]);  // 2-way banks: free
    }
    __syncthreads();

    // coalesced write: maskT[b][(i*64+j)*100 + ch], 800 float4 of halfs
    float4* dst = (float4*)(maskT + ((size_t)b * HW_ + i * 64) * 100);
    const float4* src = (const float4*)st;
    if (tid < 800) dst[tid] = src[tid];
}

// ---------------------------------------------------------------------------
// Kernel C: reassembly + pixel shuffle.
// grid (64 i, 16 cc, B), block (64 j, 4 cq). Thread: 4 ch x 4 subpx.
// sx [r][col][ch pad20] staged via ds_write_b128 (conflict-free).
// smask fp16 [j][100]: bulk float4 copy in; 40.0 KB total LDS -> 4 blocks/CU.
// ---------------------------------------------------------------------------
__global__ void __launch_bounds__(256)
k_reassemble(const float* __restrict__ x, const __half* __restrict__ maskT,
             float* __restrict__ out) {
    __shared__ __align__(16) __half smask[64 * 100];  // 12.8 KB
    __shared__ __align__(16) float sx[5 * 68 * 20];   // 27.2 KB
    const int tx = threadIdx.x;                    // j
    const int ty = threadIdx.y;                    // ch-quad
    const int tid = ty * 64 + tx;
    const int i = blockIdx.x;
    const int cc = blockIdx.y;
    const int b = blockIdx.z;

    // ---- mask row: fully coalesced float4 copy (800 float4 of halfs) ----
    {
        const float4* src = (const float4*)(maskT + ((size_t)b * HW_ + i * 64) * 100);
        float4* dst = (float4*)smask;
#pragma unroll
        for (int t = 0; t < 4; ++t) {
            int e = tid + t * 256;
            if (e < 800) dst[e] = src[e];
        }
    }

    // ---- x tile: per-thread float4 of 4 channels -> ds_write_b128 ----
    const float* xb = x + ((size_t)b * C_ + cc * 16 + ty * 4) * HW_;
#pragma unroll
    for (int r = 0; r < 5; ++r) {
        const int gi = i + r - 2;                  // uniform
        const bool rowok = ((unsigned)gi < 64u);   // uniform branch
        {
            float4 v = {0.f, 0.f, 0.f, 0.f};
            int gj = tx - 2;
            if (rowok && gj >= 0) {                // gj <= 61 always
                const float* p = xb + gi * W_ + gj;
                v.x = p[0];
                v.y = p[HW_];
                v.z = p[2 * HW_];
                v.w = p[3 * HW_];
            }
            *(float4*)&sx[(r * 68 + tx) * 20 + ty * 4] = v;
        }
        if (tid < 16) {                            // tail cols 64..67
            int q = tid >> 2;
            int col = 64 + (tid & 3);
            int gj = col - 2;                      // 62..65
            float4 v = {0.f, 0.f, 0.f, 0.f};
            if (rowok && gj < 64) {
                const float* p = x + ((size_t)b * C_ + cc * 16 + q * 4) * HW_ + gi * W_ + gj;
                v.x = p[0];
                v.y = p[HW_];
                v.z = p[2 * HW_];
                v.w = p[3 * HW_];
            }
            *(float4*)&sx[(r * 68 + col) * 20 + q * 4] = v;
        }
    }
    __syncthreads();

    v2f a01[4], a23[4];
#pragma unroll
    for (int cl = 0; cl < 4; ++cl) { a01[cl] = (v2f){0.f, 0.f}; a23[cl] = (v2f){0.f, 0.f}; }

    // prefetch k2=0
    float4 xq = *(const float4*)&sx[(0 * 68 + tx + 0) * 20 + ty * 4];
    __half2 h01 = *(const __half2*)&smask[tx * 100 + 0];
    __half2 h23 = *(const __half2*)&smask[tx * 100 + 2];

#pragma unroll
    for (int k2 = 0; k2 < K2_; ++k2) {
        float4 xq_c = xq;
        __half2 h01_c = h01, h23_c = h23;
        if (k2 < K2_ - 1) {
            const int kn = k2 + 1;
            const int dy = kn / 5, dx = kn % 5;
            xq  = *(const float4*)&sx[(dy * 68 + tx + dx) * 20 + ty * 4];
            h01 = *(const __half2*)&smask[tx * 100 + kn * 4];
            h23 = *(const __half2*)&smask[tx * 100 + kn * 4 + 2];
        }
        float2 f01 = __half22float2(h01_c);
        float2 f23 = __half22float2(h23_c);
        v2f m01 = (v2f){f01.x, f01.y};
        v2f m23 = (v2f){f23.x, f23.y};
        float xc[4] = {xq_c.x, xq_c.y, xq_c.z, xq_c.w};
#pragma unroll
        for (int cl = 0; cl < 4; ++cl) {
            v2f xv2 = (v2f){xc[cl], xc[cl]};
            a01[cl] = FMA2(xv2, m01, a01[cl]);
            a23[cl] = FMA2(xv2, m23, a23[cl]);
        }
    }

#pragma unroll
    for (int cl = 0; cl < 4; ++cl) {
        int c = cc * 16 + ty * 4 + cl;
        float* op = out + (((size_t)(b * C_ + c) * 128 + 2 * i) * 128) + 2 * tx;
        *(float2*)op         = float2{a01[cl].x, a01[cl].y};
        *(float2*)(op + 128) = float2{a23[cl].x, a23[cl].y};
    }
}

// ---------------------------------------------------------------------------
extern "C" void kernel_launch(void* const* d_in, const int* in_sizes, int n_in,
                              void* d_out, int out_size, void* d_ws, size_t ws_size,
                              hipStream_t stream) {
    const float* x       = (const float*)d_in[0];
    const float* w_comp  = (const float*)d_in[1];
    const float* bn_g    = (const float*)d_in[2];
    const float* bn_b    = (const float*)d_in[3];
    const float* bn_m    = (const float*)d_in[4];
    const float* bn_v    = (const float*)d_in[5];
    const float* w_enc   = (const float*)d_in[6];
    float* out = (float*)d_out;

    float* ws    = (float*)d_ws;
    float* wTc   = ws;                               // 16384 floats
    float* wTe   = ws + 16384;                       // 59904 floats (stride 26)
    float* act   = ws + 16384 + 59904;               // 1,048,576 floats
    __half* maskT = (__half*)(act + (size_t)B_ * COMP_ * HW_);  // 1,638,400 halfs

    k_transpose<<<289, 256, 0, stream>>>(w_comp, w_enc, wTc, wTe);
    k_compress<<<dim3(64, B_), dim3(64, 8, 2), 0, stream>>>(x, wTc, bn_g, bn_b, bn_m, bn_v, act);
    k_encoder<<<dim3(64, B_), dim3(64, 4, 4), 0, stream>>>(act, wTe, maskT);
    k_reassemble<<<dim3(64, 16, B_), dim3(64, 4), 0, stream>>>(x, maskT, out);
}